// Round 6
// baseline (1325.641 us; speedup 1.0000x reference)
//
#include <hip/hip_runtime.h>
#include <hip/hip_bf16.h>
#include <stdint.h>

#define E_ 8
#define B_ 16384
#define N_ 64
#define H_ 512
#define A_ 8
#define D_ 64

typedef __hip_bfloat16 bf16;
typedef __attribute__((ext_vector_type(8))) short s8v;     // 8 x bf16 (4 VGPRs)
typedef __attribute__((ext_vector_type(4))) short s4v;     // 4 x bf16
typedef __attribute__((ext_vector_type(4))) float f4v;     // MFMA accum

__device__ __forceinline__ float bf2f(bf16 v) { return __bfloat162float(v); }
__device__ __forceinline__ bf16 f2bf(float v) { return __float2bfloat16(v); }
__device__ __forceinline__ short f2bfs(float v) {
    bf16 b = f2bf(v); short s; __builtin_memcpy(&s, &b, 2); return s;
}
__device__ __forceinline__ float bfs2f(short s) {
    bf16 b; __builtin_memcpy(&b, &s, 2); return bf2f(b);
}
__device__ __forceinline__ float leaky(float v) { return (v >= 0.f) ? v : 0.01f * v; }

__device__ __forceinline__ void async_load16(const void* g, void* l) {
    __builtin_amdgcn_global_load_lds(
        (const __attribute__((address_space(1))) void*)g,
        (__attribute__((address_space(3))) void*)l, 16, 0, 0);
}

// Swizzled LDS short-offset for a row-major [rows][64]-short tile:
// slot (row, g) holds data K-group (g ^ (row&7)).
__device__ __forceinline__ int swz_off(int row, int krow) {
    return row * 64 + (((krow >> 3) ^ (row & 7)) << 3);
}
__device__ __forceinline__ int swz_el(int row, int col) {
    return row * 64 + ((((col >> 3) ^ (row & 7)) << 3) | (col & 7));
}

template <int CB>
__device__ __forceinline__ void xcd_map(int x, int nBm, int& bm, int& bn) {
    if ((nBm & 7) == 0) {
        int j = x & 7, s = x >> 3;
        bn = s & ((1 << CB) - 1);
        bm = ((s >> CB) << 3) | j;
    } else {
        bm = x >> CB;
        bn = x & ((1 << CB) - 1);
    }
}

// ---------------------------------------------------------------------------
// BatchNorm statistics
// ---------------------------------------------------------------------------
__global__ __launch_bounds__(256) void bnPart(const float* __restrict__ states,
                                              float* __restrict__ part) {
    int blk = blockIdx.x;
    int e = blk >> 6, sl = blk & 63;
    int tid = threadIdx.x, n = tid & 63, rg = tid >> 6;
    const float* base = states + ((long)e * B_ + (long)sl * 256) * 64;
    float s1 = 0.f, s2 = 0.f;
    for (int i = 0; i < 64; ++i) {
        float v = base[(rg + i * 4) * 64 + n];
        s1 += v; s2 += v * v;
    }
    __shared__ float sh[2][4][64];
    sh[0][rg][n] = s1; sh[1][rg][n] = s2;
    __syncthreads();
    if (tid < 64) {
        float t1 = sh[0][0][n] + sh[0][1][n] + sh[0][2][n] + sh[0][3][n];
        float t2 = sh[1][0][n] + sh[1][1][n] + sh[1][2][n] + sh[1][3][n];
        part[((long)blk * 64 + n) * 2 + 0] = t1;
        part[((long)blk * 64 + n) * 2 + 1] = t2;
    }
}

__global__ void bnFin(const float* __restrict__ part, float* __restrict__ mu_rstd) {
    int idx = blockIdx.x * blockDim.x + threadIdx.x;  // e*64+n
    if (idx >= E_ * 64) return;
    int e = idx >> 6, n = idx & 63;
    float s1 = 0.f, s2 = 0.f;
    for (int sl = 0; sl < 64; ++sl) {
        s1 += part[(((long)e * 64 + sl) * 64 + n) * 2 + 0];
        s2 += part[(((long)e * 64 + sl) * 64 + n) * 2 + 1];
    }
    float mu = s1 / (float)B_;
    float var = s2 / (float)B_ - mu * mu;
    mu_rstd[idx * 2 + 0] = mu;
    mu_rstd[idx * 2 + 1] = rsqrtf(var + 1e-5f);
}

// Fold BN into encoder weight: WencfT[e][h][n] = W_enc[e][n][h]*rstd[e][n]
__global__ void foldEnc(const float* __restrict__ W_enc, const float* __restrict__ b_enc,
                        const float* __restrict__ mu_rstd,
                        bf16* __restrict__ WencfT, float* __restrict__ bencf) {
    int idx = blockIdx.x * 256 + threadIdx.x;  // E*H = 4096
    int e = idx >> 9, h = idx & 511;
    float acc = b_enc[e * 512 + h];
    for (int n = 0; n < 64; ++n) {
        float mu = mu_rstd[(e * 64 + n) * 2 + 0];
        float rs = mu_rstd[(e * 64 + n) * 2 + 1];
        float w = W_enc[((long)e * 64 + n) * 512 + h];
        WencfT[((long)e * 512 + h) * 64 + n] = f2bf(w * rs);
        acc -= mu * rs * w;
    }
    bencf[e * 512 + h] = acc;
}

// ---------------------------------------------------------------------------
// All weight packing + pre_actions f32->bf16, one dispatch.
// ---------------------------------------------------------------------------
__global__ __launch_bounds__(256) void packAll(
    const float* __restrict__ W_pre, const float* __restrict__ W_actor,
    const float* __restrict__ Wsel, const float* __restrict__ Wk,
    const float* __restrict__ Wv, const float* __restrict__ wm,
    const float* __restrict__ wl, const float* __restrict__ pre_actions,
    bf16* __restrict__ WpreT, bf16* __restrict__ WactorT, bf16* __restrict__ WselT,
    bf16* __restrict__ WkvaT, bf16* __restrict__ WmlT, bf16* __restrict__ pa_bf) {
    int bx = blockIdx.x, tid = threadIdx.x;
    if (bx < 2048) {
        const float* in = (bx < 1024) ? W_pre : W_actor;
        bf16* out = (bx < 1024) ? WpreT : WactorT;
        int idx = (bx & 1023) * 256 + tid;
        int n = idx >> 9, k = idx & 511;
        out[idx] = f2bf(in[k * 512 + n]);
    } else if (bx < 3072) {
        int idx = (bx - 2048) * 256 + tid;
        int n = idx >> 9, h = idx & 511;
        int a = n >> 6, dd = n & 63;
        WselT[idx] = f2bf(Wsel[((long)a * 512 + h) * 64 + dd]);
    } else if (bx < 5120) {
        int idx = (bx - 3072) * 256 + tid;
        int n = idx >> 9, h = idx & 511;
        int a = n >> 7, j = n & 127;
        const float* src = (j < 64) ? Wk : Wv;
        WkvaT[idx] = f2bf(src[((long)a * 512 + h) * 64 + (j & 63)]);
    } else if (bx < 5376) {
        int idx = (bx - 5120) * 256 + tid;
        int n = idx >> 9, k = idx & 511;
        float v = (n < 64) ? wm[k * 64 + n] : wl[k * 64 + (n - 64)];
        WmlT[idx] = f2bf(v);
    } else {
        int i = (bx - 5376) * 256 + tid;  // 8192 blocks cover B*512/4
        float4 v = ((const float4*)pre_actions)[i];
        bf16 o[4] = {f2bf(v.x), f2bf(v.y), f2bf(v.z), f2bf(v.w)};
        __builtin_memcpy(pa_bf + (long)i * 4, o, 8);
    }
}

// ---------------------------------------------------------------------------
// Generic MFMA GEMM (pre/sel/actor/ml), unchanged from r4.
// ---------------------------------------------------------------------------
template <int ACT, int OUTF, bool HAS_BIAS, int CB>
__global__ __launch_bounds__(256) void gemm_bt(
    const bf16* __restrict__ Ag, const bf16* __restrict__ Bg,
    const float* __restrict__ bias, const float* __restrict__ bias2,
    void* __restrict__ out, void* __restrict__ out2,
    int M, int Nn, int K, long sA, long sB, long sBias, long sO) {
    const int tid = threadIdx.x, lane = tid & 63, wid = tid >> 6;
    const int wm = wid >> 1, wn = wid & 1;
    int bm, bn;
    xcd_map<CB>(blockIdx.x, gridDim.x >> CB, bm, bn);
    const int bz = blockIdx.z;
    const bf16* Aptr = Ag + (long)bz * sA + (long)bm * 128 * K;
    const bf16* Bptr = Bg + (long)bz * sB + (long)bn * 128 * K;

    __shared__ __align__(16) short sAl[128 * 64];
    __shared__ __align__(16) short sBl[128 * 64];

    const int srow = lane >> 3;
    const int scol = (((lane & 7) ^ srow) << 3);

    f4v acc[4][4];
#pragma unroll
    for (int i = 0; i < 4; ++i)
#pragma unroll
        for (int j = 0; j < 4; ++j) acc[i][j] = f4v{0.f, 0.f, 0.f, 0.f};

    for (int k0 = 0; k0 < K; k0 += 64) {
#pragma unroll
        for (int i = 0; i < 4; ++i) {
            int r = (wid * 4 + i) * 8 + srow;
            async_load16(Aptr + (long)r * K + k0 + scol, (char*)sAl + (wid * 4 + i) * 1024);
            async_load16(Bptr + (long)r * K + k0 + scol, (char*)sBl + (wid * 4 + i) * 1024);
        }
        __syncthreads();
#pragma unroll
        for (int kk = 0; kk < 64; kk += 32) {
            int krow = kk + (lane >> 4) * 8;
            s8v af[4], bfr[4];
#pragma unroll
            for (int mi = 0; mi < 4; ++mi)
                af[mi] = *(const s8v*)(sAl + swz_off(wm * 64 + mi * 16 + (lane & 15), krow));
#pragma unroll
            for (int ni = 0; ni < 4; ++ni)
                bfr[ni] = *(const s8v*)(sBl + swz_off(wn * 64 + ni * 16 + (lane & 15), krow));
#pragma unroll
            for (int mi = 0; mi < 4; ++mi)
#pragma unroll
                for (int ni = 0; ni < 4; ++ni)
                    acc[mi][ni] = __builtin_amdgcn_mfma_f32_16x16x32_bf16(
                        af[mi], bfr[ni], acc[mi][ni], 0, 0, 0);
        }
        __syncthreads();
    }

    long m0 = (long)bm * 128 + wm * 64;
    long n0 = (long)bn * 128 + wn * 64;
#pragma unroll
    for (int mi = 0; mi < 4; ++mi)
#pragma unroll
        for (int ni = 0; ni < 4; ++ni)
#pragma unroll
            for (int r = 0; r < 4; ++r) {
                long gm = m0 + mi * 16 + (lane >> 4) * 4 + r;
                long gn = n0 + ni * 16 + (lane & 15);
                float v = acc[mi][ni][r];
                if constexpr (HAS_BIAS) v += bias[sBias * bz + gn];
                if constexpr (ACT == 1) v = leaky(v);
                if constexpr (ACT == 2) v = fmaxf(v, 0.f);
                if constexpr (OUTF == 0) {
                    ((bf16*)out)[(long)bz * sO + gm * Nn + gn] = f2bf(v);
                } else if constexpr (OUTF == 1) {
                    ((float*)out)[(long)bz * sO + gm * Nn + gn] = v;
                } else {  // OUTF == 2: mean / clipped logstd
                    if (gn < 64) {
                        ((float*)out)[gm * 64 + gn] = v + bias[gn];
                    } else {
                        float w = v + bias2[gn - 64];
                        w = fminf(fmaxf(w, -20.f), 2.f);
                        ((float*)out2)[gm * 64 + (gn - 64)] = w;
                    }
                }
            }
}

// ---------------------------------------------------------------------------
// Fused encoder -> keys/vals -> softmax-attention.  One block = 16 b's.
// 512 threads (8 waves).  Rows ordered e*16+b (16-row MFMA tiles e-uniform).
// Per pass (2 heads): per k0, recompute 128x64 enc panel in LDS (B-frags
// direct global from L2-hot WencfT), then kv MFMA with B direct-global from
// WkvaT -- no vmcnt(0) barrier on B.  encs never touch HBM.
// ---------------------------------------------------------------------------
__global__ __launch_bounds__(512, 4) void enc_kv_attn(
    const float* __restrict__ states, const bf16* __restrict__ WencfT,
    const float* __restrict__ bencf, const bf16* __restrict__ WkvaT,
    const float* __restrict__ bv, const float* __restrict__ sel,
    float* __restrict__ actor_f32, bf16* __restrict__ attn_bf) {
    const int tid = threadIdx.x, lane = tid & 63, wid = tid >> 6;
    const int cl = lane & 15, quad = lane >> 4;
    const int wm = wid >> 1, wn = wid & 1;
    const long bgBase = (long)blockIdx.x * 16;

    // LDS: panel(16K, also pTile0 f32 + initial states staging) | pTile1(16K)
    //      | sel(4K) | logit(1K) | w(1K)  = 38 KB
    __shared__ __align__(16) char smem[38912];
    short* sPanel = (short*)smem;
    float* sPT0   = (float*)smem;
    float* sPT1   = (float*)(smem + 16384);
    short* sSel   = (short*)(smem + 32768);
    float* sLogit = (float*)(smem + 36864);
    float* sW     = (float*)(smem + 37888);

    // ---- stage states f32->bf16 into panel region, swizzled [row=e*16+b][n]
    {
        int row = tid >> 2, seg = tid & 3;
        int e = row >> 4, bl = row & 15;
        const float* sp = states + ((long)e * B_ + bgBase + bl) * 64 + seg * 16;
        short tmp[16];
#pragma unroll
        for (int q = 0; q < 4; ++q) {
            float4 v = ((const float4*)sp)[q];
            tmp[q * 4 + 0] = f2bfs(v.x); tmp[q * 4 + 1] = f2bfs(v.y);
            tmp[q * 4 + 2] = f2bfs(v.z); tmp[q * 4 + 3] = f2bfs(v.w);
        }
        *(s8v*)(sPanel + row * 64 + (((seg * 2) ^ (row & 7)) << 3)) = *(s8v*)tmp;
        *(s8v*)(sPanel + row * 64 + (((seg * 2 + 1) ^ (row & 7)) << 3)) = *(s8v*)(tmp + 8);
    }
    __syncthreads();

    // ---- hoist encoder A-frags (wave = e = wid) into registers; states die
    s8v encA[2];
    {
        int arow = wid * 16 + cl;
#pragma unroll
        for (int kk = 0; kk < 2; ++kk) {
            int g = (kk * 4 + quad) ^ (arow & 7);
            encA[kk] = *(const s8v*)(sPanel + arow * 64 + (g << 3));
        }
    }
    __syncthreads();

    for (int p = 0; p < 4; ++p) {
        const int head = 2 * p + wn;
        // stage sel slices for heads 2p, 2p+1 (bf16)
        {
            int hh = tid >> 8, r = tid & 255, b = r >> 4, dg = r & 15;
            float4 v = *(const float4*)(sel + (bgBase + b) * 512 + (2 * p + hh) * 64 + dg * 4);
            s4v t4 = {f2bfs(v.x), f2bfs(v.y), f2bfs(v.z), f2bfs(v.w)};
            *(s4v*)(sSel + hh * 1024 + b * 64 + dg * 4) = t4;
        }
        f4v acc[2][8];
#pragma unroll
        for (int mi = 0; mi < 2; ++mi)
#pragma unroll
            for (int ni = 0; ni < 8; ++ni) acc[mi][ni] = f4v{0.f, 0.f, 0.f, 0.f};

        const bf16* Bp = WkvaT + ((long)(head * 128 + cl) * 512) + quad * 8;

        for (int k0 = 0; k0 < 8; ++k0) {
            // --- enc panel: wave covers e = wid; out rows wid*16.., cols k0*64..
            {
                f4v ea[4];
#pragma unroll
                for (int ni = 0; ni < 4; ++ni) ea[ni] = f4v{0.f, 0.f, 0.f, 0.f};
#pragma unroll
                for (int kk = 0; kk < 2; ++kk) {
#pragma unroll
                    for (int ni = 0; ni < 4; ++ni) {
                        const bf16* wp = WencfT +
                            ((long)(wid * 512 + k0 * 64 + ni * 16 + cl)) * 64 + kk * 32 + quad * 8;
                        s8v bfw = *(const s8v*)wp;
                        ea[ni] = __builtin_amdgcn_mfma_f32_16x16x32_bf16(encA[kk], bfw, ea[ni], 0, 0, 0);
                    }
                }
                float bb = bencf[wid * 512 + k0 * 64 + lane];
#pragma unroll
                for (int ni = 0; ni < 4; ++ni) {
                    float bni = __shfl(bb, ni * 16 + cl);
#pragma unroll
                    for (int r = 0; r < 4; ++r) {
                        float v = leaky(ea[ni][r] + bni);
                        int prow = wid * 16 + quad * 4 + r;
                        sPanel[swz_el(prow, ni * 16 + cl)] = f2bfs(v);
                    }
                }
            }
            __syncthreads();
            // --- kv partial: A from panel, B direct global (L2-hot) ---
#pragma unroll
            for (int kk = 0; kk < 2; ++kk) {
                s8v af[2];
#pragma unroll
                for (int mi = 0; mi < 2; ++mi) {
                    int arow = wm * 32 + mi * 16 + cl;
                    int g = (kk * 4 + quad) ^ (arow & 7);
                    af[mi] = *(const s8v*)(sPanel + arow * 64 + (g << 3));
                }
                s8v bfr[8];
#pragma unroll
                for (int ni = 0; ni < 8; ++ni)
                    bfr[ni] = *(const s8v*)(Bp + (long)ni * 16 * 512 + k0 * 64 + kk * 32);
#pragma unroll
                for (int mi = 0; mi < 2; ++mi)
#pragma unroll
                    for (int ni = 0; ni < 8; ++ni)
                        acc[mi][ni] = __builtin_amdgcn_mfma_f32_16x16x32_bf16(
                            af[mi], bfr[ni], acc[mi][ni], 0, 0, 0);
            }
            __syncthreads();
        }

        // ---- logits from keys accumulators (ni 0..3): rows e=2wm+mi, b=quad*4+r
        {
            float selv[4][4];
#pragma unroll
            for (int ni = 0; ni < 4; ++ni)
#pragma unroll
                for (int r = 0; r < 4; ++r)
                    selv[ni][r] = bfs2f(sSel[wn * 1024 + (quad * 4 + r) * 64 + ni * 16 + cl]);
#pragma unroll
            for (int mi = 0; mi < 2; ++mi) {
                float s[4];
#pragma unroll
                for (int r = 0; r < 4; ++r)
                    s[r] = selv[0][r] * acc[mi][0][r] + selv[1][r] * acc[mi][1][r] +
                           selv[2][r] * acc[mi][2][r] + selv[3][r] * acc[mi][3][r];
#pragma unroll
                for (int r = 0; r < 4; ++r) {
                    s[r] += __shfl_xor(s[r], 1);
                    s[r] += __shfl_xor(s[r], 2);
                    s[r] += __shfl_xor(s[r], 4);
                    s[r] += __shfl_xor(s[r], 8);
                }
                if (cl == 0) {
#pragma unroll
                    for (int r = 0; r < 4; ++r)
                        sLogit[wn * 128 + (quad * 4 + r) * 8 + (2 * wm + mi)] = s[r] * 0.125f;
                }
            }
        }
        __syncthreads();
        // ---- softmax over e ----
        if (tid < 256) {
            int hh = tid >> 7, b = (tid >> 3) & 15, e = tid & 7;
            const float* lp = sLogit + hh * 128 + b * 8;
            float mx = lp[0];
#pragma unroll
            for (int j = 1; j < 8; ++j) mx = fmaxf(mx, lp[j]);
            float sum = 0.f;
#pragma unroll
            for (int j = 0; j < 8; ++j) sum += __expf(lp[j] - mx);
            sW[hh * 128 + b * 8 + e] = __expf(lp[e] - mx) / sum;
        }
        __syncthreads();
        // ---- weighted val partials (ni 4..7) -> per-wm partial tiles ----
        {
            float wv[2][4];
#pragma unroll
            for (int mi = 0; mi < 2; ++mi)
#pragma unroll
                for (int r = 0; r < 4; ++r)
                    wv[mi][r] = sW[wn * 128 + (quad * 4 + r) * 8 + (2 * wm + mi)];
            float bvv = bv[head * 64 + lane];
            float* pT = (wn == 0) ? sPT0 : sPT1;
#pragma unroll
            for (int ni = 4; ni < 8; ++ni) {
                float bni = __shfl(bvv, (ni - 4) * 16 + cl);
#pragma unroll
                for (int r = 0; r < 4; ++r) {
                    float v0 = leaky(acc[0][ni][r] + bni);
                    float v1 = leaky(acc[1][ni][r] + bni);
                    pT[wm * 1024 + (quad * 4 + r) * 64 + (ni - 4) * 16 + cl] =
                        wv[0][r] * v0 + wv[1][r] * v1;
                }
            }
        }
        __syncthreads();
        // ---- final cross-wm sum + store ----
        {
            int hh = tid >> 8, r = tid & 255, b = r >> 4, dg = r & 15;
            const float* pT = hh ? sPT1 : sPT0;
            float o0 = 0.f, o1 = 0.f, o2 = 0.f, o3 = 0.f;
#pragma unroll
            for (int w = 0; w < 4; ++w) {
                float4 t = *(const float4*)(pT + w * 1024 + b * 64 + dg * 4);
                o0 += t.x; o1 += t.y; o2 += t.z; o3 += t.w;
            }
            long og = (bgBase + b) * 512 + (2 * p + hh) * 64 + dg * 4;
            float4 f4 = {o0, o1, o2, o3};
            *(float4*)(actor_f32 + og) = f4;
            bf16 ob[4] = {f2bf(o0), f2bf(o1), f2bf(o2), f2bf(o3)};
            __builtin_memcpy(attn_bf + og, ob, 8);
        }
        __syncthreads();  // protect pT0(panel)/sSel before next pass
    }
}

// ---------------------------------------------------------------------------
extern "C" void kernel_launch(void* const* d_in, const int* in_sizes, int n_in,
                              void* d_out, int out_size, void* d_ws, size_t ws_size,
                              hipStream_t stream) {
    (void)in_sizes; (void)n_in; (void)out_size; (void)ws_size;
    const float* states      = (const float*)d_in[0];
    const float* pre_actions = (const float*)d_in[1];
    const float* W_enc       = (const float*)d_in[2];
    const float* b_enc       = (const float*)d_in[3];
    const float* W_pre       = (const float*)d_in[4];
    const float* b_pre       = (const float*)d_in[5];
    const float* Wk          = (const float*)d_in[6];
    const float* Wsel        = (const float*)d_in[7];
    const float* Wv          = (const float*)d_in[8];
    const float* bv          = (const float*)d_in[9];
    const float* W_actor     = (const float*)d_in[10];
    const float* b_actor     = (const float*)d_in[11];
    const float* W_mean      = (const float*)d_in[12];
    const float* b_mean      = (const float*)d_in[13];
    const float* W_logstd    = (const float*)d_in[14];
    const float* b_logstd    = (const float*)d_in[15];

    char* ws = (char*)d_ws;
    size_t off = 0;
    auto alloc = [&](size_t bytes) -> void* {
        void* p = ws + off;
        off = (off + bytes + 255) & ~(size_t)255;
        return p;
    };
    float* mu_rstd = (float*)alloc((size_t)E_ * 64 * 2 * 4);
    float* bnpart  = (float*)alloc((size_t)E_ * 64 * 64 * 2 * 4);
    bf16* WencfT   = (bf16*)alloc((size_t)E_ * 512 * 64 * 2);
    float* bencf   = (float*)alloc((size_t)E_ * 512 * 4);
    bf16* WpreT    = (bf16*)alloc((size_t)512 * 512 * 2);
    bf16* WselT    = (bf16*)alloc((size_t)512 * 512 * 2);
    bf16* WkvaT    = (bf16*)alloc((size_t)1024 * 512 * 2);
    bf16* WactorT  = (bf16*)alloc((size_t)512 * 512 * 2);
    bf16* WmlT     = (bf16*)alloc((size_t)128 * 512 * 2);
    bf16* pa_bf    = (bf16*)alloc((size_t)B_ * 512 * 2);   // aliased later as p_attn
    bf16* p_pre    = (bf16*)alloc((size_t)B_ * 512 * 2);   // aliased later as p_x
    float* p_sel   = (float*)alloc((size_t)B_ * 512 * 4);
    bf16* p_attn = pa_bf;   // pre_actions bf16 dead after pre GEMM
    bf16* p_x    = p_pre;   // pre dead after sel GEMM

    // --- prep ---
    packAll<<<13568, 256, 0, stream>>>(W_pre, W_actor, Wsel, Wk, Wv, W_mean, W_logstd,
                                       pre_actions, WpreT, WactorT, WselT, WkvaT, WmlT,
                                       pa_bf);
    bnPart<<<512, 256, 0, stream>>>(states, bnpart);
    bnFin<<<2, 256, 0, stream>>>(bnpart, mu_rstd);
    foldEnc<<<16, 256, 0, stream>>>(W_enc, b_enc, mu_rstd, WencfT, bencf);

    // --- pre / sel (full B) ---
    gemm_bt<1, 0, true, 2><<<dim3((B_ / 128) << 2, 1, 1), 256, 0, stream>>>(
        pa_bf, WpreT, b_pre, nullptr, p_pre, nullptr, B_, 512, 512, 0, 0, 0, 0);
    gemm_bt<0, 1, false, 2><<<dim3((B_ / 128) << 2, 1, 1), 256, 0, stream>>>(
        p_pre, WselT, nullptr, nullptr, p_sel, nullptr, B_, 512, 512, 0, 0, 0, 0);

    // --- fused encoder -> keys/vals -> attention (single dispatch) ---
    float* actor_out = (float*)d_out + 2L * B_ * 64;
    enc_kv_attn<<<B_ / 16, 512, 0, stream>>>(states, WencfT, bencf, WkvaT, bv,
                                             p_sel, actor_out, p_attn);

    // --- actor + heads ---
    gemm_bt<2, 0, true, 2><<<dim3((B_ / 128) << 2, 1, 1), 256, 0, stream>>>(
        p_attn, WactorT, b_actor, nullptr, p_x, nullptr, B_, 512, 512, 0, 0, 0, 0);
    gemm_bt<0, 2, false, 0><<<dim3(B_ / 128, 1, 1), 256, 0, stream>>>(
        p_x, WmlT, b_mean, b_logstd, (float*)d_out, (float*)d_out + (long)B_ * 64,
        B_, 128, 512, 0, 0, 0, 0);
}